// Round 2
// baseline (36.759 us; speedup 1.0000x reference)
//
#include <hip/hip_runtime.h>
#include <math.h>

// Problem constants (fixed by setup_inputs).
namespace {
constexpr int Bc = 2, Nc = 6, Cc = 81, Hc = 112, Wc = 200, Mc = 20;
constexpr int BN    = Bc * Nc;      // 12
constexpr int HW    = Hc * Wc;      // 22400 (divisible by 4)
constexpr int NPIX  = BN * HW;      // 268800
constexpr int NQUAD = NPIX / 4;     // 67200
constexpr int QPB   = 64;           // pixel-quads per block (one per lane)
constexpr int NBLK  = NQUAD / QPB;  // 1050 — exact
constexpr float kAlpha = 0.25f;
constexpr float kFgW   = 13.0f;
constexpr float kBgW   = 1.0f;
constexpr float kInvDS = 0.125f;    // 1/8 exact pow-2: x*kInvDS == x/8
}

// Block = 256 threads = 4 waves. Each block owns 64 pixel-quads (256 pixels).
// Wave y accumulates sum(exp(logit_c)) and the target logit over classes
// c = y, y+4, y+8, ... (interleaved 4-way class split) with float4 loads.
// Partials combine via LDS; epilogue is one thread per pixel (focal loss,
// 20-box fg mask, weight), then block reduce -> one atomicAdd of partial/NPIX.
__global__ __launch_bounds__(256) void ddn_loss_kernel(
    const float* __restrict__ logits,   // [BN, C, H, W]
    const int*   __restrict__ target,   // [BN, H, W]
    const float* __restrict__ boxes,    // [BN, M, 4] (x, y, w, h)
    float* __restrict__ out)            // [1]
{
    __shared__ float smem[4][QPB][9];   // [wave][quad][4×s, 4×x, pad] — 9-stride: conflict-free
    __shared__ float wsum[4];

    const int t    = threadIdx.x;
    const int lane = t & 63;
    const int y    = t >> 6;

    const int quad = blockIdx.x * QPB + lane;
    const int pix0 = quad * 4;
    const int bn   = pix0 / HW;
    const int hw   = pix0 - bn * HW;

    const float4* lp =
        reinterpret_cast<const float4*>(logits + (size_t)bn * Cc * HW + hw);
    const int4 tg =
        *reinterpret_cast<const int4*>(target + (size_t)bn * HW + hw);

    float s0 = 0.f, s1 = 0.f, s2 = 0.f, s3 = 0.f;
    float x0 = 0.f, x1 = 0.f, x2 = 0.f, x3 = 0.f;
    #pragma unroll 5
    for (int i = 0; i < 20; ++i) {
        const int c = y + i * 4;              // ≤ 79, always valid
        const float4 v = lp[(size_t)c * (HW / 4)];
        s0 += __expf(v.x);
        s1 += __expf(v.y);
        s2 += __expf(v.z);
        s3 += __expf(v.w);
        if (c == tg.x) x0 = v.x;
        if (c == tg.y) x1 = v.y;
        if (c == tg.z) x2 = v.z;
        if (c == tg.w) x3 = v.w;
    }
    if (y == 0) {                             // leftover class 80
        const int c = 80;
        const float4 v = lp[(size_t)c * (HW / 4)];
        s0 += __expf(v.x);
        s1 += __expf(v.y);
        s2 += __expf(v.z);
        s3 += __expf(v.w);
        if (c == tg.x) x0 = v.x;
        if (c == tg.y) x1 = v.y;
        if (c == tg.z) x2 = v.z;
        if (c == tg.w) x3 = v.w;
    }
    smem[y][lane][0] = s0; smem[y][lane][1] = s1;
    smem[y][lane][2] = s2; smem[y][lane][3] = s3;
    smem[y][lane][4] = x0; smem[y][lane][5] = x1;
    smem[y][lane][6] = x2; smem[y][lane][7] = x3;
    __syncthreads();

    // Epilogue: one thread per pixel (256 threads = 64 quads × 4 pixels).
    const int q = t >> 2;
    const int p = t & 3;
    const float s = smem[0][q][p]     + smem[1][q][p]
                  + smem[2][q][p]     + smem[3][q][p];
    const float x = smem[0][q][4 + p] + smem[1][q][4 + p]
                  + smem[2][q][4 + p] + smem[3][q][4 + p];

    const int pixel = (blockIdx.x * QPB + q) * 4 + p;
    const int bn2   = pixel / HW;
    const int rem   = pixel - bn2 * HW;
    const int h     = rem / Wc;
    const int w     = rem - h * Wc;

    const float lpt  = x - __logf(s);         // log_pt
    const float om   = 1.f - __expf(lpt);     // 1 - pt
    const float loss = -kAlpha * om * om * lpt;

    const float* bx = boxes + (size_t)bn2 * Mc * 4;
    bool fg = false;
    const float hf = (float)h, wf = (float)w;
    #pragma unroll
    for (int m = 0; m < Mc; ++m) {
        const float bxx = bx[m * 4 + 0];
        const float bxy = bx[m * 4 + 1];
        const float u1 = floorf(bxx * kInvDS);
        const float v1 = floorf(bxy * kInvDS);
        const float u2 = ceilf((bxx + bx[m * 4 + 2]) * kInvDS);
        const float v2 = ceilf((bxy + bx[m * 4 + 3]) * kInvDS);
        fg |= (hf >= v1) & (hf < v2) & (wf >= u1) & (wf < u2);
    }
    float local = loss * (fg ? kFgW : kBgW);

    // Wave64 reduce, cross-wave via LDS, one atomic per block.
    #pragma unroll
    for (int off = 32; off > 0; off >>= 1)
        local += __shfl_down(local, off, 64);
    if ((t & 63) == 0) wsum[t >> 6] = local;
    __syncthreads();
    if (t == 0)
        atomicAdd(out, (wsum[0] + wsum[1] + wsum[2] + wsum[3])
                           * (1.0f / (float)NPIX));
}

extern "C" void kernel_launch(void* const* d_in, const int* in_sizes, int n_in,
                              void* d_out, int out_size, void* d_ws, size_t ws_size,
                              hipStream_t stream) {
    const float* logits = (const float*)d_in[0];  // depth_logits f32
    const int*   target = (const int*)d_in[1];    // depth_target i32
    const float* boxes  = (const float*)d_in[2];  // gt_bboxes_2d f32
    float* out = (float*)d_out;

    // We accumulate via atomics and the harness doesn't re-poison between
    // replays — zero the scalar output every launch (async memset is
    // graph-capture safe).
    hipMemsetAsync(out, 0, sizeof(float), stream);

    ddn_loss_kernel<<<NBLK, 256, 0, stream>>>(logits, target, boxes, out);
}